// Round 8
// baseline (218.020 us; speedup 1.0000x reference)
//
#include <hip/hip_runtime.h>
#include <cmath>

// MultimodalCrossAttention on MI355X (gfx950), bf16 MFMA pipeline.
// B=2, Sx=Sc=2048, D_MODEL=1024, H=16, hd=64.

typedef __bf16 bf16x8 __attribute__((ext_vector_type(8)));
typedef __bf16 bf16x4 __attribute__((ext_vector_type(4)));
typedef float f32x4 __attribute__((ext_vector_type(4)));

#define MFMA(A, B, C) __builtin_amdgcn_mfma_f32_16x16x32_bf16(A, B, C, 0, 0, 0)
#define GLL16(g, l)                                                        \
  __builtin_amdgcn_global_load_lds(                                        \
      (const __attribute__((address_space(1))) unsigned int*)(g),          \
      (__attribute__((address_space(3))) unsigned int*)(l), 16, 0, 0)

// ---------------- fused fp32 -> bf16 convert for all 5 tensors ----------------
__global__ __launch_bounds__(256) void cvt_all_kernel(
    const float* __restrict__ x, const float* __restrict__ ctx,
    const float* __restrict__ Wq, const float* __restrict__ Wv,
    const float* __restrict__ Wo, __bf16* __restrict__ xb, __bf16* __restrict__ cb,
    __bf16* __restrict__ Wqb, __bf16* __restrict__ Wvb, __bf16* __restrict__ Wob) {
  int i = blockIdx.x * 256 + threadIdx.x;
  const float* src;
  __bf16* dst;
  int off;
  if (i < 1048576) { src = x; dst = xb; off = 0; }
  else if (i < 2097152) { src = ctx; dst = cb; off = 1048576; }
  else if (i < 2359296) { src = Wq; dst = Wqb; off = 2097152; }
  else if (i < 2621440) { src = Wv; dst = Wvb; off = 2359296; }
  else { src = Wo; dst = Wob; off = 2621440; }
  int j = i - off;
  float4 f = ((const float4*)src)[j];
  bf16x4 o;
  o[0] = (__bf16)f.x; o[1] = (__bf16)f.y; o[2] = (__bf16)f.z; o[3] = (__bf16)f.w;
  ((bf16x4*)dst)[j] = o;
}

// ---------------- Projection GEMM: 128x128 tile, BK=32, dbuf GLL staging ----------------
// Merged QKV: blocks x<64: A = xb||cb vs Wq (Q rows 0..4095 w/ RoPE+scale, K rows
// 4096..8191 w/ RoPE); x>=64: A = cb vs Wv -> V transposed [b,h,d,s].
__global__ __launch_bounds__(256) void gemm_proj(const __bf16* __restrict__ A0,
                                                 const __bf16* __restrict__ W0,
                                                 void* __restrict__ outQ,
                                                 void* __restrict__ outK,
                                                 void* __restrict__ outV) {
  const int tid = threadIdx.x;
  const int wave = tid >> 6, lane = tid & 63, quad = lane >> 4, l15 = lane & 15;
  const int mw = wave >> 1, nw = wave & 1;
  const int n0 = blockIdx.y * 128;

  int m0 = blockIdx.x * 128;
  const __bf16* A = A0;
  const __bf16* W = W0;
  bool vmode = false;
  if (blockIdx.x >= 64) {
    m0 = (blockIdx.x - 64) * 128;
    A = A0 + (size_t)4096 * 1024;  // cb
    W = W0 + (size_t)1024 * 1024;  // Wvb
    vmode = true;
  }

  __shared__ __attribute__((aligned(16))) __bf16 As[2][4096];  // 16KB
  __shared__ __attribute__((aligned(16))) __bf16 Ws[2][4096];  // 16KB

  int goff[2];
#pragma unroll
  for (int jj = 0; jj < 2; jj++) {
    const int s = jj * 256 + tid;
    const int row = s >> 2;
    const int kcg = (s & 3) ^ ((row >> 1) & 3);
    goff[jj] = row * 1024 + kcg * 8;
  }
  const __bf16* Ag = A + (size_t)m0 * 1024;
  const __bf16* Wg = W + (size_t)n0 * 1024;
  const int ldsoff0 = wave * 512;
  const int ldsoff1 = 2048 + wave * 512;

  const int sw = (l15 >> 1) & 3;
  int afoff[4], wfoff[4];
#pragma unroll
  for (int t = 0; t < 4; t++) {
    afoff[t] = (mw * 64 + t * 16 + l15) * 32 + (quad ^ sw) * 8;
    wfoff[t] = (nw * 64 + t * 16 + l15) * 32 + (quad ^ sw) * 8;
  }

  f32x4 acc[4][4] = {};

  auto stage = [&](int buf, int k0) {
    GLL16(Ag + goff[0] + k0, &As[buf][ldsoff0]);
    GLL16(Ag + goff[1] + k0, &As[buf][ldsoff1]);
    GLL16(Wg + goff[0] + k0, &Ws[buf][ldsoff0]);
    GLL16(Wg + goff[1] + k0, &Ws[buf][ldsoff1]);
  };
  auto compute = [&](int buf) {
    bf16x8 af[4], wf[4];
#pragma unroll
    for (int t = 0; t < 4; t++) af[t] = *(const bf16x8*)&As[buf][afoff[t]];
#pragma unroll
    for (int t = 0; t < 4; t++) wf[t] = *(const bf16x8*)&Ws[buf][wfoff[t]];
#pragma unroll
    for (int mt = 0; mt < 4; mt++)
#pragma unroll
      for (int nt = 0; nt < 4; nt++) acc[mt][nt] = MFMA(af[mt], wf[nt], acc[mt][nt]);
  };

  stage(0, 0);
  for (int k0 = 0; k0 < 1024; k0 += 64) {
    __syncthreads();
    if (k0 + 32 < 1024) stage(1, k0 + 32);
    compute(0);
    __syncthreads();
    if (k0 + 64 < 1024) stage(0, k0 + 64);
    compute(1);
  }

  // Epilogue. C/D: row = quad*4+r (per 16-tile), col = l15.
  if (!vmode) {
    const int isK = (m0 >= 4096);
    __bf16* O = (__bf16*)(isK ? outK : outQ);
    const float qsc = isK ? 1.0f : 0.18033688f;  // 0.125*log2(e) folded into Q
    const int mb = m0 & 4095;
#pragma unroll
    for (int nt = 0; nt < 4; nt++) {
      const int n = n0 + nw * 64 + nt * 16 + l15;
      const int h = n >> 6, d = n & 63, p = d >> 1;
      // theta^(-p/32) / 2pi  (angle in REVOLUTIONS for v_sin/v_cos)
      const float invf_rev =
          __builtin_amdgcn_exp2f(-((float)p * 0.41524101f + 2.6514961f));
#pragma unroll
      for (int mt = 0; mt < 4; mt++) {
#pragma unroll
        for (int r = 0; r < 4; r++) {
          const int row = mb + mw * 64 + mt * 16 + quad * 4 + r;
          const int s = row & 2047, b = row >> 11;
          float v = acc[mt][nt][r];
          float pv = __shfl_xor(v, 1, 64);
          float fr = __builtin_amdgcn_fractf((float)s * invf_rev);
          float sn = __builtin_amdgcn_sinf(fr);
          float cs = __builtin_amdgcn_cosf(fr);
          float res = (lane & 1) ? (pv * sn + v * cs) : (v * cs - pv * sn);
          O[((size_t)(b * 16 + h) * 2048 + s) * 64 + d] = (__bf16)(res * qsc);
        }
      }
    }
  } else {
    __bf16* O = (__bf16*)outV;
#pragma unroll
    for (int nt = 0; nt < 4; nt++) {
      const int n = n0 + nw * 64 + nt * 16 + l15;
      const int h = n >> 6, d = n & 63;
#pragma unroll
      for (int mt = 0; mt < 4; mt++) {
        const int rowb = m0 + mw * 64 + mt * 16 + quad * 4;
        const int s = rowb & 2047, b = rowb >> 11;
        bf16x4 o;
#pragma unroll
        for (int r = 0; r < 4; r++) o[r] = (__bf16)acc[mt][nt][r];
        *(bf16x4*)(O + ((size_t)(b * 16 + h) * 64 + d) * 2048 + s) = o;
      }
    }
  }
}

// ---------------- Out-proj GEMM: 64x64 tile, 1024 blocks (4/CU), fp32 out + bias ----------------
__global__ __launch_bounds__(256) void gemm_out(const __bf16* __restrict__ A,
                                                const __bf16* __restrict__ W,
                                                float* __restrict__ O,
                                                const float* __restrict__ bias) {
  const int tid = threadIdx.x;
  const int wave = tid >> 6, lane = tid & 63, quad = lane >> 4, l15 = lane & 15;
  const int mw = wave >> 1, nw = wave & 1;
  const int m0 = blockIdx.x * 64, n0 = blockIdx.y * 64;

  __shared__ __attribute__((aligned(16))) __bf16 As[2][2048];  // 8KB
  __shared__ __attribute__((aligned(16))) __bf16 Ws[2][2048];  // 8KB

  // slot s = tid: row = s>>2, kc_lds = s&3, kc_g = kc_lds ^ ((row>>1)&3)
  const int srow = tid >> 2;
  const int goff = srow * 1024 + (((tid & 3) ^ ((srow >> 1) & 3)) * 8);
  const __bf16* Ag = A + (size_t)m0 * 1024;
  const __bf16* Wg = W + (size_t)n0 * 1024;
  const int ldsoff = wave * 512;

  const int sw = (l15 >> 1) & 3;
  int afoff[2], wfoff[2];
#pragma unroll
  for (int t = 0; t < 2; t++) {
    afoff[t] = (mw * 32 + t * 16 + l15) * 32 + (quad ^ sw) * 8;
    wfoff[t] = (nw * 32 + t * 16 + l15) * 32 + (quad ^ sw) * 8;
  }

  f32x4 acc[2][2] = {};

  auto stage = [&](int buf, int k0) {
    GLL16(Ag + goff + k0, &As[buf][ldsoff]);
    GLL16(Wg + goff + k0, &Ws[buf][ldsoff]);
  };
  auto compute = [&](int buf) {
    bf16x8 af[2], wf[2];
#pragma unroll
    for (int t = 0; t < 2; t++) af[t] = *(const bf16x8*)&As[buf][afoff[t]];
#pragma unroll
    for (int t = 0; t < 2; t++) wf[t] = *(const bf16x8*)&Ws[buf][wfoff[t]];
#pragma unroll
    for (int mt = 0; mt < 2; mt++)
#pragma unroll
      for (int nt = 0; nt < 2; nt++) acc[mt][nt] = MFMA(af[mt], wf[nt], acc[mt][nt]);
  };

  stage(0, 0);
  for (int k0 = 0; k0 < 1024; k0 += 64) {
    __syncthreads();
    if (k0 + 32 < 1024) stage(1, k0 + 32);
    compute(0);
    __syncthreads();
    if (k0 + 64 < 1024) stage(0, k0 + 64);
    compute(1);
  }

#pragma unroll
  for (int nt = 0; nt < 2; nt++) {
    const int n = n0 + nw * 32 + nt * 16 + l15;
    const float bv = bias[n];
#pragma unroll
    for (int mt = 0; mt < 2; mt++) {
#pragma unroll
      for (int r = 0; r < 4; r++) {
        const int row = m0 + mw * 32 + mt * 16 + quad * 4 + r;
        O[(size_t)row * 1024 + n] = acc[mt][nt][r] + bv;
      }
    }
  }
}

// ---------------- Flash attention: BQ=64, XCD-swizzled, fixed-ref softmax ----------------
// 1D grid 1024. id -> xcd=id&7, j=id>>3: bh = xcd*4 + (j&3), q0 = (j>>2)*64.
// All 32 q-blocks of one bh land on one XCD => per-XCD K/V working set
// = 4 bh x 512KB = 2MB < 4MB L2 (staging L2-resident, proven r7).
// Block 256 = 4 waves; wave owns 16 q. LDS 40KB -> 4 blocks/CU (grid gives 4/CU).
__global__ __launch_bounds__(256) void attn_kernel(const __bf16* __restrict__ Q,
                                                   const __bf16* __restrict__ K,
                                                   const __bf16* __restrict__ Vt,
                                                   __bf16* __restrict__ Aout) {
  const int tid = threadIdx.x;
  const int wave = tid >> 6, lane = tid & 63, quad = lane >> 4, l15 = lane & 15;
  const int id = blockIdx.x;
  const int j = id >> 3;
  const int bh = ((id & 7) << 2) | (j & 3);
  const int q0 = (j >> 2) << 6;

  const __bf16* Qb = Q + (size_t)bh * (2048 * 64);
  const __bf16* Kb = K + (size_t)bh * (2048 * 64);
  const __bf16* Vb = Vt + (size_t)bh * (64 * 2048);

  __shared__ __attribute__((aligned(16))) __bf16 Kbuf[2][4096];      // 16KB
  __shared__ __attribute__((aligned(16))) __bf16 Vbuf[2][4096];      // 16KB
  __shared__ __attribute__((aligned(16))) __bf16 Plds[4][8][16][8];  // 8KB

  // Q B-frags (loop-invariant, pre-scaled): n=l15->q, k=quad*8+j->d
  const __bf16* qp = Qb + (size_t)(q0 + wave * 16 + l15) * 64 + quad * 8;
  const bf16x8 qf0 = *(const bf16x8*)qp;
  const bf16x8 qf1 = *(const bf16x8*)(qp + 32);

  // Staging: slot s: LDS[r=s>>3][cs=s&7] = global[r][cs^(r&7)]. 2 slots/lane/tile.
  const int s0 = (wave * 2 + 0) * 64 + lane;
  const int s1 = (wave * 2 + 1) * 64 + lane;
  const int r0 = s0 >> 3, c0 = (s0 & 7) ^ (r0 & 7);
  const int r1 = s1 >> 3, c1 = (s1 & 7) ^ (r1 & 7);
  const __bf16* kg0 = Kb + r0 * 64 + c0 * 8;
  const __bf16* kg1 = Kb + r1 * 64 + c1 * 8;
  const __bf16* vg0 = Vb + r0 * 2048 + c0 * 8;
  const __bf16* vg1 = Vb + r1 * 2048 + c1 * 8;
  const int kldsA = (wave * 2 + 0) * 512;
  const int kldsB = (wave * 2 + 1) * 512;

  // Frag read offsets: row r=nt*16+l15 -> r&7 == l15&7 (nt-invariant).
  const int offF0 = l15 * 64 + ((quad ^ (l15 & 7)) * 8);
  const int offF1 = l15 * 64 + (((4 + quad) ^ (l15 & 7)) * 8);

  float rsum = 0.f;
  f32x4 oT[4] = {};

  auto stage = [&](int buf, int kt) {
    GLL16(kg0 + kt * 64, &Kbuf[buf][kldsA]);
    GLL16(kg1 + kt * 64, &Kbuf[buf][kldsB]);
    GLL16(vg0 + kt, &Vbuf[buf][kldsA]);
    GLL16(vg1 + kt, &Vbuf[buf][kldsB]);
  };
  auto compute = [&](int buf) {
    // ---- S^T = K·Q^T ----
    f32x4 sT[4];
#pragma unroll
    for (int nt = 0; nt < 4; nt++) {
      bf16x8 kf0 = *(const bf16x8*)&Kbuf[buf][nt * 1024 + offF0];
      bf16x8 kf1 = *(const bf16x8*)&Kbuf[buf][nt * 1024 + offF1];
      f32x4 z = {};
      z = MFMA(kf0, qf0, z);
      sT[nt] = MFMA(kf1, qf1, z);
    }
    // ---- p = exp2(S'), per-lane sum, pack to P^T LDS ----
#pragma unroll
    for (int nt = 0; nt < 4; nt++) {
      bf16x4 pb;
#pragma unroll
      for (int r = 0; r < 4; r++) {
        float pe = __builtin_amdgcn_exp2f(sT[nt][r]);
        rsum += pe;
        pb[r] = (__bf16)pe;
      }
      const int chunk = nt * 2 + (quad >> 1);
      *(bf16x4*)&Plds[wave][chunk][l15 ^ ((chunk & 3) << 1)][(quad & 1) * 4] = pb;
    }
    // ---- P^T B-frags (wave-private, in-order DS) ----
    bf16x8 pf0 = *(const bf16x8*)&Plds[wave][quad][l15 ^ (quad << 1)][0];
    bf16x8 pf1 = *(const bf16x8*)&Plds[wave][4 + quad][l15 ^ (quad << 1)][0];
    // ---- O^T += V^T·P^T ----
#pragma unroll
    for (int nt = 0; nt < 4; nt++) {
      bf16x8 vf0 = *(const bf16x8*)&Vbuf[buf][nt * 1024 + offF0];
      bf16x8 vf1 = *(const bf16x8*)&Vbuf[buf][nt * 1024 + offF1];
      oT[nt] = MFMA(vf0, pf0, oT[nt]);
      oT[nt] = MFMA(vf1, pf1, oT[nt]);
    }
  };

  stage(0, 0);
  for (int kt = 0; kt < 2048; kt += 128) {
    __syncthreads();
    if (kt + 64 < 2048) stage(1, kt + 64);
    compute(0);
    __syncthreads();
    if (kt + 128 < 2048) stage(0, kt + 128);
    compute(1);
  }

  // Epilogue: reduce l across quads (2 shfls), normalize, store.
  const int b = bh >> 4, h = bh & 15;
  float l = rsum;
  l += __shfl_xor(l, 16, 64);
  l += __shfl_xor(l, 32, 64);
  const float inv = 1.f / l;
  const int q = q0 + wave * 16 + l15;
#pragma unroll
  for (int nt = 0; nt < 4; nt++) {
    bf16x4 o;
#pragma unroll
    for (int r = 0; r < 4; r++) o[r] = (__bf16)(oT[nt][r] * inv);
    *(bf16x4*)&Aout[((size_t)(b * 2048 + q)) * 1024 + h * 64 + nt * 16 + quad * 4] = o;
  }
}

extern "C" void kernel_launch(void* const* d_in, const int* in_sizes, int n_in,
                              void* d_out, int out_size, void* d_ws, size_t ws_size,
                              hipStream_t stream) {
  const float* x   = (const float*)d_in[0];
  const float* ctx = (const float*)d_in[1];
  const float* Wq  = (const float*)d_in[2];
  const float* Wv  = (const float*)d_in[3];
  const float* Wo  = (const float*)d_in[4];
  const float* bo  = (const float*)d_in[5];

  char* ws = (char*)d_ws;
  const size_t MB = 1024 * 1024;
  __bf16* xb   = (__bf16*)(ws + 0 * MB);   // [4096,1024]; contiguous with cb
  __bf16* cb   = (__bf16*)(ws + 8 * MB);   // [4096,1024]
  __bf16* Wqb  = (__bf16*)(ws + 16 * MB);  // contiguous with Wvb
  __bf16* Wvb  = (__bf16*)(ws + 18 * MB);
  __bf16* Wob  = (__bf16*)(ws + 20 * MB);
  __bf16* qh   = (__bf16*)(ws + 22 * MB);  // [b,h,s,d], pre-scaled by 0.18034
  __bf16* kh   = (__bf16*)(ws + 30 * MB);  // [b,h,s,d]
  __bf16* vt   = (__bf16*)(ws + 38 * MB);  // [b,h,d,s]
  __bf16* attn = xb;  // xb dead after QK projection

  cvt_all_kernel<<<11264, 256, 0, stream>>>(x, ctx, Wq, Wv, Wo, xb, cb, Wqb, Wvb, Wob);

  gemm_proj<<<dim3(96, 8), 256, 0, stream>>>(xb, Wqb, (void*)qh, (void*)kh, (void*)vt);

  attn_kernel<<<1024, 256, 0, stream>>>(qh, kh, vt, attn);

  gemm_out<<<dim3(64, 16), 256, 0, stream>>>(attn, Wob, (float*)d_out, bo);
}

// Round 9
// 209.550 us; speedup vs baseline: 1.0404x; 1.0404x over previous
//
#include <hip/hip_runtime.h>
#include <cmath>

// MultimodalCrossAttention on MI355X (gfx950), bf16 MFMA pipeline.
// B=2, Sx=Sc=2048, D_MODEL=1024, H=16, hd=64.

typedef __bf16 bf16x8 __attribute__((ext_vector_type(8)));
typedef __bf16 bf16x4 __attribute__((ext_vector_type(4)));
typedef float f32x4 __attribute__((ext_vector_type(4)));

#define MFMA(A, B, C) __builtin_amdgcn_mfma_f32_16x16x32_bf16(A, B, C, 0, 0, 0)
#define GLL16(g, l)                                                        \
  __builtin_amdgcn_global_load_lds(                                        \
      (const __attribute__((address_space(1))) unsigned int*)(g),          \
      (__attribute__((address_space(3))) unsigned int*)(l), 16, 0, 0)

// ---------------- fused fp32 -> bf16 convert, 2 float4/thread ----------------
// ranges (in float4 units): x[0,1048576) ctx[..2097152) Wq[..2359296)
// Wv[..2621440) Wo[..2883584). All boundaries multiples of 512 -> both of a
// thread's indices (base, base+256) land in the same tensor.
__global__ __launch_bounds__(256) void cvt_all_kernel(
    const float* __restrict__ x, const float* __restrict__ ctx,
    const float* __restrict__ Wq, const float* __restrict__ Wv,
    const float* __restrict__ Wo, __bf16* __restrict__ xb, __bf16* __restrict__ cb,
    __bf16* __restrict__ Wqb, __bf16* __restrict__ Wvb, __bf16* __restrict__ Wob) {
  int base = blockIdx.x * 512 + threadIdx.x;
  const float* src;
  __bf16* dst;
  int off;
  if (base < 1048576) { src = x; dst = xb; off = 0; }
  else if (base < 2097152) { src = ctx; dst = cb; off = 1048576; }
  else if (base < 2359296) { src = Wq; dst = Wqb; off = 2097152; }
  else if (base < 2621440) { src = Wv; dst = Wvb; off = 2359296; }
  else { src = Wo; dst = Wob; off = 2621440; }
#pragma unroll
  for (int jj = 0; jj < 2; jj++) {
    int j = base - off + jj * 256;
    float4 f = ((const float4*)src)[j];
    bf16x4 o;
    o[0] = (__bf16)f.x; o[1] = (__bf16)f.y; o[2] = (__bf16)f.z; o[3] = (__bf16)f.w;
    ((bf16x4*)dst)[j] = o;
  }
}

// ---------------- Projection GEMM: 128x128 tile, BK=32, dbuf GLL staging ----------------
// Merged QKV: blocks x<64: A = xb||cb vs Wq (Q rows 0..4095 w/ RoPE+scale, K rows
// 4096..8191 w/ RoPE); x>=64: A = cb vs Wv -> V transposed [b,h,d,s].
__global__ __launch_bounds__(256) void gemm_proj(const __bf16* __restrict__ A0,
                                                 const __bf16* __restrict__ W0,
                                                 void* __restrict__ outQ,
                                                 void* __restrict__ outK,
                                                 void* __restrict__ outV) {
  const int tid = threadIdx.x;
  const int wave = tid >> 6, lane = tid & 63, quad = lane >> 4, l15 = lane & 15;
  const int mw = wave >> 1, nw = wave & 1;
  const int n0 = blockIdx.y * 128;

  int m0 = blockIdx.x * 128;
  const __bf16* A = A0;
  const __bf16* W = W0;
  bool vmode = false;
  if (blockIdx.x >= 64) {
    m0 = (blockIdx.x - 64) * 128;
    A = A0 + (size_t)4096 * 1024;  // cb
    W = W0 + (size_t)1024 * 1024;  // Wvb
    vmode = true;
  }

  __shared__ __attribute__((aligned(16))) __bf16 As[2][4096];  // 16KB
  __shared__ __attribute__((aligned(16))) __bf16 Ws[2][4096];  // 16KB

  int goff[2];
#pragma unroll
  for (int jj = 0; jj < 2; jj++) {
    const int s = jj * 256 + tid;
    const int row = s >> 2;
    const int kcg = (s & 3) ^ ((row >> 1) & 3);
    goff[jj] = row * 1024 + kcg * 8;
  }
  const __bf16* Ag = A + (size_t)m0 * 1024;
  const __bf16* Wg = W + (size_t)n0 * 1024;
  const int ldsoff0 = wave * 512;
  const int ldsoff1 = 2048 + wave * 512;

  const int sw = (l15 >> 1) & 3;
  int afoff[4], wfoff[4];
#pragma unroll
  for (int t = 0; t < 4; t++) {
    afoff[t] = (mw * 64 + t * 16 + l15) * 32 + (quad ^ sw) * 8;
    wfoff[t] = (nw * 64 + t * 16 + l15) * 32 + (quad ^ sw) * 8;
  }

  f32x4 acc[4][4] = {};

  auto stage = [&](int buf, int k0) {
    GLL16(Ag + goff[0] + k0, &As[buf][ldsoff0]);
    GLL16(Ag + goff[1] + k0, &As[buf][ldsoff1]);
    GLL16(Wg + goff[0] + k0, &Ws[buf][ldsoff0]);
    GLL16(Wg + goff[1] + k0, &Ws[buf][ldsoff1]);
  };
  auto compute = [&](int buf) {
    bf16x8 af[4], wf[4];
#pragma unroll
    for (int t = 0; t < 4; t++) af[t] = *(const bf16x8*)&As[buf][afoff[t]];
#pragma unroll
    for (int t = 0; t < 4; t++) wf[t] = *(const bf16x8*)&Ws[buf][wfoff[t]];
#pragma unroll
    for (int mt = 0; mt < 4; mt++)
#pragma unroll
      for (int nt = 0; nt < 4; nt++) acc[mt][nt] = MFMA(af[mt], wf[nt], acc[mt][nt]);
  };

  stage(0, 0);
  for (int k0 = 0; k0 < 1024; k0 += 64) {
    __syncthreads();
    if (k0 + 32 < 1024) stage(1, k0 + 32);
    compute(0);
    __syncthreads();
    if (k0 + 64 < 1024) stage(0, k0 + 64);
    compute(1);
  }

  // Epilogue. C/D: row = quad*4+r (per 16-tile), col = l15.
  if (!vmode) {
    const int isK = (m0 >= 4096);
    __bf16* O = (__bf16*)(isK ? outK : outQ);
    const float qsc = isK ? 1.0f : 0.18033688f;  // 0.125*log2(e) folded into Q
    const int mb = m0 & 4095;
#pragma unroll
    for (int nt = 0; nt < 4; nt++) {
      const int n = n0 + nw * 64 + nt * 16 + l15;
      const int h = n >> 6, d = n & 63, p = d >> 1;
      // theta^(-p/32) / 2pi  (angle in REVOLUTIONS for v_sin/v_cos)
      const float invf_rev =
          __builtin_amdgcn_exp2f(-((float)p * 0.41524101f + 2.6514961f));
#pragma unroll
      for (int mt = 0; mt < 4; mt++) {
#pragma unroll
        for (int r = 0; r < 4; r++) {
          const int row = mb + mw * 64 + mt * 16 + quad * 4 + r;
          const int s = row & 2047, b = row >> 11;
          float v = acc[mt][nt][r];
          float pv = __shfl_xor(v, 1, 64);
          float fr = __builtin_amdgcn_fractf((float)s * invf_rev);
          float sn = __builtin_amdgcn_sinf(fr);
          float cs = __builtin_amdgcn_cosf(fr);
          float res = (lane & 1) ? (pv * sn + v * cs) : (v * cs - pv * sn);
          O[((size_t)(b * 16 + h) * 2048 + s) * 64 + d] = (__bf16)(res * qsc);
        }
      }
    }
  } else {
    __bf16* O = (__bf16*)outV;
#pragma unroll
    for (int nt = 0; nt < 4; nt++) {
      const int n = n0 + nw * 64 + nt * 16 + l15;
      const int h = n >> 6, d = n & 63;
#pragma unroll
      for (int mt = 0; mt < 4; mt++) {
        const int rowb = m0 + mw * 64 + mt * 16 + quad * 4;
        const int s = rowb & 2047, b = rowb >> 11;
        bf16x4 o;
#pragma unroll
        for (int r = 0; r < 4; r++) o[r] = (__bf16)acc[mt][nt][r];
        *(bf16x4*)(O + ((size_t)(b * 16 + h) * 64 + d) * 2048 + s) = o;
      }
    }
  }
}

// ---------------- Out-proj GEMM: 64x64 tile, 1024 blocks (4/CU), fp32 out + bias ----------------
__global__ __launch_bounds__(256) void gemm_out(const __bf16* __restrict__ A,
                                                const __bf16* __restrict__ W,
                                                float* __restrict__ O,
                                                const float* __restrict__ bias) {
  const int tid = threadIdx.x;
  const int wave = tid >> 6, lane = tid & 63, quad = lane >> 4, l15 = lane & 15;
  const int mw = wave >> 1, nw = wave & 1;
  const int m0 = blockIdx.x * 64, n0 = blockIdx.y * 64;

  __shared__ __attribute__((aligned(16))) __bf16 As[2][2048];  // 8KB
  __shared__ __attribute__((aligned(16))) __bf16 Ws[2][2048];  // 8KB

  const int srow = tid >> 2;
  const int goff = srow * 1024 + (((tid & 3) ^ ((srow >> 1) & 3)) * 8);
  const __bf16* Ag = A + (size_t)m0 * 1024;
  const __bf16* Wg = W + (size_t)n0 * 1024;
  const int ldsoff = wave * 512;

  const int sw = (l15 >> 1) & 3;
  int afoff[2], wfoff[2];
#pragma unroll
  for (int t = 0; t < 2; t++) {
    afoff[t] = (mw * 32 + t * 16 + l15) * 32 + (quad ^ sw) * 8;
    wfoff[t] = (nw * 32 + t * 16 + l15) * 32 + (quad ^ sw) * 8;
  }

  f32x4 acc[2][2] = {};

  auto stage = [&](int buf, int k0) {
    GLL16(Ag + goff + k0, &As[buf][ldsoff]);
    GLL16(Wg + goff + k0, &Ws[buf][ldsoff]);
  };
  auto compute = [&](int buf) {
    bf16x8 af[2], wf[2];
#pragma unroll
    for (int t = 0; t < 2; t++) af[t] = *(const bf16x8*)&As[buf][afoff[t]];
#pragma unroll
    for (int t = 0; t < 2; t++) wf[t] = *(const bf16x8*)&Ws[buf][wfoff[t]];
#pragma unroll
    for (int mt = 0; mt < 2; mt++)
#pragma unroll
      for (int nt = 0; nt < 2; nt++) acc[mt][nt] = MFMA(af[mt], wf[nt], acc[mt][nt]);
  };

  stage(0, 0);
  for (int k0 = 0; k0 < 1024; k0 += 64) {
    __syncthreads();
    if (k0 + 32 < 1024) stage(1, k0 + 32);
    compute(0);
    __syncthreads();
    if (k0 + 64 < 1024) stage(0, k0 + 64);
    compute(1);
  }

#pragma unroll
  for (int nt = 0; nt < 2; nt++) {
    const int n = n0 + nw * 32 + nt * 16 + l15;
    const float bv = bias[n];
#pragma unroll
    for (int mt = 0; mt < 2; mt++) {
#pragma unroll
      for (int r = 0; r < 4; r++) {
        const int row = m0 + mw * 32 + mt * 16 + quad * 4 + r;
        O[(size_t)row * 1024 + n] = acc[mt][nt][r] + bv;
      }
    }
  }
}

// ---------------- Flash attention: BQ=128, XCD-swizzled, quad-buffered K/V ----------------
// 1D grid 512. id -> xcd=id&7, j=id>>3: bh = xcd*4 + (j&3), q0 = (j>>2)*128.
// K/V in 4 buffers (2 pairs); ONE barrier per 128-k: prefetch pair p^1 right
// after the barrier, compute pair p (two 64-k passes) -> by the next barrier
// the prefetch has been in flight a full compute-pair, so the vmcnt(0) drain
// is ~free and barrier count halves. LDS 80KB -> 2 blocks/CU (= grid's 2/CU).
__global__ __launch_bounds__(256) void attn_kernel(const __bf16* __restrict__ Q,
                                                   const __bf16* __restrict__ K,
                                                   const __bf16* __restrict__ Vt,
                                                   __bf16* __restrict__ Aout) {
  const int tid = threadIdx.x;
  const int wave = tid >> 6, lane = tid & 63, quad = lane >> 4, l15 = lane & 15;
  const int id = blockIdx.x;
  const int j = id >> 3;
  const int bh = ((id & 7) << 2) | (j & 3);
  const int q0 = (j >> 2) << 7;

  const __bf16* Qb = Q + (size_t)bh * (2048 * 64);
  const __bf16* Kb = K + (size_t)bh * (2048 * 64);
  const __bf16* Vb = Vt + (size_t)bh * (64 * 2048);

  __shared__ __attribute__((aligned(16))) __bf16 Kbuf[4][4096];        // 32KB
  __shared__ __attribute__((aligned(16))) __bf16 Vbuf[4][4096];        // 32KB
  __shared__ __attribute__((aligned(16))) __bf16 Plds[4][2][8][16][8];  // 16KB

  // Q B-frags (loop-invariant, pre-scaled): n=l15->q, k=quad*8+j->d
  bf16x8 qf[2][2];
#pragma unroll
  for (int c = 0; c < 2; c++) {
    const __bf16* qp = Qb + (size_t)(q0 + wave * 32 + c * 16 + l15) * 64 + quad * 8;
    qf[c][0] = *(const bf16x8*)qp;
    qf[c][1] = *(const bf16x8*)(qp + 32);
  }

  // Staging: slot s: LDS[r=s>>3][cs=s&7] = global[r][cs^(r&7)]. 2 slots/lane/tile.
  const int s0 = (wave * 2 + 0) * 64 + lane;
  const int s1 = (wave * 2 + 1) * 64 + lane;
  const int r0 = s0 >> 3, c0 = (s0 & 7) ^ (r0 & 7);
  const int r1 = s1 >> 3, c1 = (s1 & 7) ^ (r1 & 7);
  const __bf16* kg0 = Kb + r0 * 64 + c0 * 8;
  const __bf16* kg1 = Kb + r1 * 64 + c1 * 8;
  const __bf16* vg0 = Vb + r0 * 2048 + c0 * 8;
  const __bf16* vg1 = Vb + r1 * 2048 + c1 * 8;
  const int kldsA = (wave * 2 + 0) * 512;
  const int kldsB = (wave * 2 + 1) * 512;

  // Frag read offsets: row r=nt*16+l15 -> r&7 == l15&7 (nt-invariant).
  const int offF0 = l15 * 64 + ((quad ^ (l15 & 7)) * 8);
  const int offF1 = l15 * 64 + (((4 + quad) ^ (l15 & 7)) * 8);

  f32x4 rs4[2] = {};   // vectorized row-sum accumulators (short dep chains)
  f32x4 oT[4][2] = {};

  auto stage = [&](int buf, int kt) {
    GLL16(kg0 + kt * 64, &Kbuf[buf][kldsA]);
    GLL16(kg1 + kt * 64, &Kbuf[buf][kldsB]);
    GLL16(vg0 + kt, &Vbuf[buf][kldsA]);
    GLL16(vg1 + kt, &Vbuf[buf][kldsB]);
  };
  auto compute = [&](int buf) {
    // ---- S^T = K·Q^T ----
    f32x4 sT[2][4];
#pragma unroll
    for (int nt = 0; nt < 4; nt++) {
      bf16x8 kf0 = *(const bf16x8*)&Kbuf[buf][nt * 1024 + offF0];
      bf16x8 kf1 = *(const bf16x8*)&Kbuf[buf][nt * 1024 + offF1];
#pragma unroll
      for (int c = 0; c < 2; c++) {
        f32x4 z = {};
        z = MFMA(kf0, qf[c][0], z);
        sT[c][nt] = MFMA(kf1, qf[c][1], z);
      }
    }
    // ---- p = exp2(S'), vectorized sums, pack to P^T LDS ----
#pragma unroll
    for (int c = 0; c < 2; c++) {
#pragma unroll
      for (int nt = 0; nt < 4; nt++) {
        bf16x4 pb;
        f32x4 pe;
#pragma unroll
        for (int r = 0; r < 4; r++) {
          pe[r] = __builtin_amdgcn_exp2f(sT[c][nt][r]);
          pb[r] = (__bf16)pe[r];
        }
        rs4[c] += pe;  // 4 independent component chains
        const int chunk = nt * 2 + (quad >> 1);
        *(bf16x4*)&Plds[wave][c][chunk][l15 ^ ((chunk & 3) << 1)][(quad & 1) * 4] = pb;
      }
    }
    // ---- P^T B-frags (wave-private, in-order DS) ----
    bf16x8 pf[2][2];
#pragma unroll
    for (int c = 0; c < 2; c++) {
      pf[c][0] = *(const bf16x8*)&Plds[wave][c][quad][l15 ^ (quad << 1)][0];
      pf[c][1] = *(const bf16x8*)&Plds[wave][c][4 + quad][l15 ^ (quad << 1)][0];
    }
    // ---- O^T += V^T·P^T ----
#pragma unroll
    for (int nt = 0; nt < 4; nt++) {
      bf16x8 vf0 = *(const bf16x8*)&Vbuf[buf][nt * 1024 + offF0];
      bf16x8 vf1 = *(const bf16x8*)&Vbuf[buf][nt * 1024 + offF1];
#pragma unroll
      for (int c = 0; c < 2; c++) {
        oT[nt][c] = MFMA(vf0, pf[c][0], oT[nt][c]);
        oT[nt][c] = MFMA(vf1, pf[c][1], oT[nt][c]);
      }
    }
  };

  stage(0, 0);
  stage(1, 64);
  for (int kt = 0; kt < 2048; kt += 128) {
    const int p = (kt >> 7) & 1;  // active pair: bufs {2p, 2p+1}
    __syncthreads();
    if (kt + 128 < 2048) {
      stage(2 * (p ^ 1), kt + 128);
      stage(2 * (p ^ 1) + 1, kt + 192);
    }
    compute(2 * p);
    compute(2 * p + 1);
  }

  // Epilogue: l = sum of rs4 components, reduce across quads, normalize, store.
  const int b = bh >> 4, h = bh & 15;
#pragma unroll
  for (int c = 0; c < 2; c++) {
    float l = (rs4[c][0] + rs4[c][1]) + (rs4[c][2] + rs4[c][3]);
    l += __shfl_xor(l, 16, 64);
    l += __shfl_xor(l, 32, 64);
    const float inv = 1.f / l;
    const int q = q0 + wave * 32 + c * 16 + l15;
#pragma unroll
    for (int nt = 0; nt < 4; nt++) {
      bf16x4 o;
#pragma unroll
      for (int r = 0; r < 4; r++) o[r] = (__bf16)(oT[nt][c][r] * inv);
      *(bf16x4*)&Aout[((size_t)(b * 2048 + q)) * 1024 + h * 64 + nt * 16 + quad * 4] = o;
    }
  }
}

extern "C" void kernel_launch(void* const* d_in, const int* in_sizes, int n_in,
                              void* d_out, int out_size, void* d_ws, size_t ws_size,
                              hipStream_t stream) {
  const float* x   = (const float*)d_in[0];
  const float* ctx = (const float*)d_in[1];
  const float* Wq  = (const float*)d_in[2];
  const float* Wv  = (const float*)d_in[3];
  const float* Wo  = (const float*)d_in[4];
  const float* bo  = (const float*)d_in[5];

  char* ws = (char*)d_ws;
  const size_t MB = 1024 * 1024;
  __bf16* xb   = (__bf16*)(ws + 0 * MB);   // [4096,1024]; contiguous with cb
  __bf16* cb   = (__bf16*)(ws + 8 * MB);   // [4096,1024]
  __bf16* Wqb  = (__bf16*)(ws + 16 * MB);  // contiguous with Wvb
  __bf16* Wvb  = (__bf16*)(ws + 18 * MB);
  __bf16* Wob  = (__bf16*)(ws + 20 * MB);
  __bf16* qh   = (__bf16*)(ws + 22 * MB);  // [b,h,s,d], pre-scaled by 0.18034
  __bf16* kh   = (__bf16*)(ws + 30 * MB);  // [b,h,s,d]
  __bf16* vt   = (__bf16*)(ws + 38 * MB);  // [b,h,d,s]
  __bf16* attn = xb;  // xb dead after QK projection

  cvt_all_kernel<<<5632, 256, 0, stream>>>(x, ctx, Wq, Wv, Wo, xb, cb, Wqb, Wvb, Wob);

  gemm_proj<<<dim3(96, 8), 256, 0, stream>>>(xb, Wqb, (void*)qh, (void*)kh, (void*)vt);

  attn_kernel<<<512, 256, 0, stream>>>(qh, kh, vt, attn);

  gemm_out<<<dim3(64, 16), 256, 0, stream>>>(attn, Wob, (float*)d_out, bo);
}

// Round 10
// 205.131 us; speedup vs baseline: 1.0628x; 1.0215x over previous
//
#include <hip/hip_runtime.h>
#include <cmath>

// MultimodalCrossAttention on MI355X (gfx950), bf16 MFMA pipeline.
// B=2, Sx=Sc=2048, D_MODEL=1024, H=16, hd=64.

typedef __bf16 bf16x8 __attribute__((ext_vector_type(8)));
typedef __bf16 bf16x4 __attribute__((ext_vector_type(4)));
typedef float f32x4 __attribute__((ext_vector_type(4)));

#define MFMA(A, B, C) __builtin_amdgcn_mfma_f32_16x16x32_bf16(A, B, C, 0, 0, 0)
#define GLL16(g, l)                                                        \
  __builtin_amdgcn_global_load_lds(                                        \
      (const __attribute__((address_space(1))) unsigned int*)(g),          \
      (__attribute__((address_space(3))) unsigned int*)(l), 16, 0, 0)

// ---------------- fused fp32 -> bf16 convert, 2 float4/thread ----------------
__global__ __launch_bounds__(256) void cvt_all_kernel(
    const float* __restrict__ x, const float* __restrict__ ctx,
    const float* __restrict__ Wq, const float* __restrict__ Wv,
    const float* __restrict__ Wo, __bf16* __restrict__ xb, __bf16* __restrict__ cb,
    __bf16* __restrict__ Wqb, __bf16* __restrict__ Wvb, __bf16* __restrict__ Wob) {
  int base = blockIdx.x * 512 + threadIdx.x;
  const float* src;
  __bf16* dst;
  int off;
  if (base < 1048576) { src = x; dst = xb; off = 0; }
  else if (base < 2097152) { src = ctx; dst = cb; off = 1048576; }
  else if (base < 2359296) { src = Wq; dst = Wqb; off = 2097152; }
  else if (base < 2621440) { src = Wv; dst = Wvb; off = 2359296; }
  else { src = Wo; dst = Wob; off = 2621440; }
#pragma unroll
  for (int jj = 0; jj < 2; jj++) {
    int j = base - off + jj * 256;
    float4 f = ((const float4*)src)[j];
    bf16x4 o;
    o[0] = (__bf16)f.x; o[1] = (__bf16)f.y; o[2] = (__bf16)f.z; o[3] = (__bf16)f.w;
    ((bf16x4*)dst)[j] = o;
  }
}

// ---------------- Projection GEMM: 128x128, triple-buffered, XCD-swizzled ----------------
// 1D grid 768. id<512: QK (A = xb||cb vs Wq): xcd=id&7, j=id>>3,
//   m0=(xcd*8+(j&7))*128, n0=(j>>3)*128  -> per-XCD A-slice 2MB + Wq 2MB = L2-resident.
// id>=512: V (A=cb vs Wv): m0=(xcd*4+(j&3))*128, n0=(j>>2)*128 -> 1MB+2MB resident.
// Rotating 3-buffer, BK=32: barrier at chunk c drains the stage issued at c-1
// (one full compute earlier, L2-hit) -> ~free. LDS 48KB -> 3 blocks/CU.
__global__ __launch_bounds__(256) void gemm_proj(const __bf16* __restrict__ A0,
                                                 const __bf16* __restrict__ W0,
                                                 void* __restrict__ outQ,
                                                 void* __restrict__ outK,
                                                 void* __restrict__ outV) {
  const int tid = threadIdx.x;
  const int wave = tid >> 6, lane = tid & 63, quad = lane >> 4, l15 = lane & 15;
  const int mw = wave >> 1, nw = wave & 1;

  const int id = blockIdx.x;
  int m0, n0;
  const __bf16* A;
  const __bf16* W;
  bool vmode;
  if (id < 512) {
    const int xcd = id & 7, j = id >> 3;
    m0 = (xcd * 8 + (j & 7)) * 128;
    n0 = (j >> 3) * 128;
    A = A0;                              // xb||cb, rows 0..8191
    W = W0;                              // Wqb
    vmode = false;
  } else {
    const int vid = id - 512;
    const int xcd = vid & 7, j = vid >> 3;
    m0 = (xcd * 4 + (j & 3)) * 128;
    n0 = (j >> 2) * 128;
    A = A0 + (size_t)4096 * 1024;        // cb
    W = W0 + (size_t)1024 * 1024;        // Wvb
    vmode = true;
  }

  __shared__ __attribute__((aligned(16))) __bf16 As[3][4096];  // 24KB
  __shared__ __attribute__((aligned(16))) __bf16 Ws[3][4096];  // 24KB

  int goff[2];
#pragma unroll
  for (int jj = 0; jj < 2; jj++) {
    const int s = jj * 256 + tid;
    const int row = s >> 2;
    const int kcg = (s & 3) ^ ((row >> 1) & 3);
    goff[jj] = row * 1024 + kcg * 8;
  }
  const __bf16* Ag = A + (size_t)m0 * 1024;
  const __bf16* Wg = W + (size_t)n0 * 1024;
  const int ldsoff0 = wave * 512;
  const int ldsoff1 = 2048 + wave * 512;

  const int sw = (l15 >> 1) & 3;
  int afoff[4], wfoff[4];
#pragma unroll
  for (int t = 0; t < 4; t++) {
    afoff[t] = (mw * 64 + t * 16 + l15) * 32 + (quad ^ sw) * 8;
    wfoff[t] = (nw * 64 + t * 16 + l15) * 32 + (quad ^ sw) * 8;
  }

  f32x4 acc[4][4] = {};

  auto stage = [&](int buf, int k0) {
    GLL16(Ag + goff[0] + k0, &As[buf][ldsoff0]);
    GLL16(Ag + goff[1] + k0, &As[buf][ldsoff1]);
    GLL16(Wg + goff[0] + k0, &Ws[buf][ldsoff0]);
    GLL16(Wg + goff[1] + k0, &Ws[buf][ldsoff1]);
  };
  auto compute = [&](int buf) {
    bf16x8 af[4], wf[4];
#pragma unroll
    for (int t = 0; t < 4; t++) af[t] = *(const bf16x8*)&As[buf][afoff[t]];
#pragma unroll
    for (int t = 0; t < 4; t++) wf[t] = *(const bf16x8*)&Ws[buf][wfoff[t]];
#pragma unroll
    for (int mt = 0; mt < 4; mt++)
#pragma unroll
      for (int nt = 0; nt < 4; nt++) acc[mt][nt] = MFMA(af[mt], wf[nt], acc[mt][nt]);
  };

  stage(0, 0);
  stage(1, 32);
  int buf = 0;
  for (int c = 0; c < 32; c++) {
    __syncthreads();  // all waves done reading the buf we're about to overwrite;
                      // drains stage issued last iter (L2-hit, ~landed)
    if (c + 2 < 32) {
      int nb = buf + 2;
      if (nb >= 3) nb -= 3;
      stage(nb, (c + 2) * 32);
    }
    compute(buf);
    buf = (buf == 2) ? 0 : buf + 1;
  }

  // Epilogue. C/D: row = quad*4+r (per 16-tile), col = l15.
  if (!vmode) {
    const int isK = (m0 >= 4096);
    __bf16* O = (__bf16*)(isK ? outK : outQ);
    const float qsc = isK ? 1.0f : 0.18033688f;  // 0.125*log2(e) folded into Q
    const int mb = m0 & 4095;
#pragma unroll
    for (int nt = 0; nt < 4; nt++) {
      const int n = n0 + nw * 64 + nt * 16 + l15;
      const int h = n >> 6, d = n & 63, p = d >> 1;
      // theta^(-p/32) / 2pi  (angle in REVOLUTIONS for v_sin/v_cos)
      const float invf_rev =
          __builtin_amdgcn_exp2f(-((float)p * 0.41524101f + 2.6514961f));
#pragma unroll
      for (int mt = 0; mt < 4; mt++) {
#pragma unroll
        for (int r = 0; r < 4; r++) {
          const int row = mb + mw * 64 + mt * 16 + quad * 4 + r;
          const int s = row & 2047, b = row >> 11;
          float v = acc[mt][nt][r];
          float pv = __shfl_xor(v, 1, 64);
          float fr = __builtin_amdgcn_fractf((float)s * invf_rev);
          float sn = __builtin_amdgcn_sinf(fr);
          float cs = __builtin_amdgcn_cosf(fr);
          float res = (lane & 1) ? (pv * sn + v * cs) : (v * cs - pv * sn);
          O[((size_t)(b * 16 + h) * 2048 + s) * 64 + d] = (__bf16)(res * qsc);
        }
      }
    }
  } else {
    __bf16* O = (__bf16*)outV;
#pragma unroll
    for (int nt = 0; nt < 4; nt++) {
      const int n = n0 + nw * 64 + nt * 16 + l15;
      const int h = n >> 6, d = n & 63;
#pragma unroll
      for (int mt = 0; mt < 4; mt++) {
        const int rowb = m0 + mw * 64 + mt * 16 + quad * 4;
        const int s = rowb & 2047, b = rowb >> 11;
        bf16x4 o;
#pragma unroll
        for (int r = 0; r < 4; r++) o[r] = (__bf16)acc[mt][nt][r];
        *(bf16x4*)(O + ((size_t)(b * 16 + h) * 64 + d) * 2048 + s) = o;
      }
    }
  }
}

// ---------------- Out-proj GEMM: 64x64, triple-buffered, XCD-swizzled ----------------
// 1D grid 1024: xcd=id&7, j=id>>3: m0=(xcd*8+(j&7))*64, n0=(j>>3)*64.
// Per-XCD: A-slice 1MB + Wo 2MB = L2-resident. LDS 24KB.
__global__ __launch_bounds__(256) void gemm_out(const __bf16* __restrict__ A,
                                                const __bf16* __restrict__ W,
                                                float* __restrict__ O,
                                                const float* __restrict__ bias) {
  const int tid = threadIdx.x;
  const int wave = tid >> 6, lane = tid & 63, quad = lane >> 4, l15 = lane & 15;
  const int mw = wave >> 1, nw = wave & 1;
  const int id = blockIdx.x;
  const int xcd = id & 7, j = id >> 3;
  const int m0 = (xcd * 8 + (j & 7)) * 64;
  const int n0 = (j >> 3) * 64;

  __shared__ __attribute__((aligned(16))) __bf16 As[3][2048];  // 12KB
  __shared__ __attribute__((aligned(16))) __bf16 Ws[3][2048];  // 12KB

  const int srow = tid >> 2;
  const int goff = srow * 1024 + (((tid & 3) ^ ((srow >> 1) & 3)) * 8);
  const __bf16* Ag = A + (size_t)m0 * 1024;
  const __bf16* Wg = W + (size_t)n0 * 1024;
  const int ldsoff = wave * 512;

  const int sw = (l15 >> 1) & 3;
  int afoff[2], wfoff[2];
#pragma unroll
  for (int t = 0; t < 2; t++) {
    afoff[t] = (mw * 32 + t * 16 + l15) * 32 + (quad ^ sw) * 8;
    wfoff[t] = (nw * 32 + t * 16 + l15) * 32 + (quad ^ sw) * 8;
  }

  f32x4 acc[2][2] = {};

  auto stage = [&](int buf, int k0) {
    GLL16(Ag + goff + k0, &As[buf][ldsoff]);
    GLL16(Wg + goff + k0, &Ws[buf][ldsoff]);
  };
  auto compute = [&](int buf) {
    bf16x8 af[2], wf[2];
#pragma unroll
    for (int t = 0; t < 2; t++) af[t] = *(const bf16x8*)&As[buf][afoff[t]];
#pragma unroll
    for (int t = 0; t < 2; t++) wf[t] = *(const bf16x8*)&Ws[buf][wfoff[t]];
#pragma unroll
    for (int mt = 0; mt < 2; mt++)
#pragma unroll
      for (int nt = 0; nt < 2; nt++) acc[mt][nt] = MFMA(af[mt], wf[nt], acc[mt][nt]);
  };

  stage(0, 0);
  stage(1, 32);
  int buf = 0;
  for (int c = 0; c < 32; c++) {
    __syncthreads();
    if (c + 2 < 32) {
      int nb = buf + 2;
      if (nb >= 3) nb -= 3;
      stage(nb, (c + 2) * 32);
    }
    compute(buf);
    buf = (buf == 2) ? 0 : buf + 1;
  }

#pragma unroll
  for (int nt = 0; nt < 2; nt++) {
    const int n = n0 + nw * 32 + nt * 16 + l15;
    const float bv = bias[n];
#pragma unroll
    for (int mt = 0; mt < 2; mt++) {
#pragma unroll
      for (int r = 0; r < 4; r++) {
        const int row = m0 + mw * 32 + mt * 16 + quad * 4 + r;
        O[(size_t)row * 1024 + n] = acc[mt][nt][r] + bv;
      }
    }
  }
}

// ---------------- Flash attention: BQ=128, XCD-swizzled, quad-buffered K/V ----------------
// (unchanged from round 9 — proven ~52 µs)
__global__ __launch_bounds__(256) void attn_kernel(const __bf16* __restrict__ Q,
                                                   const __bf16* __restrict__ K,
                                                   const __bf16* __restrict__ Vt,
                                                   __bf16* __restrict__ Aout) {
  const int tid = threadIdx.x;
  const int wave = tid >> 6, lane = tid & 63, quad = lane >> 4, l15 = lane & 15;
  const int id = blockIdx.x;
  const int j = id >> 3;
  const int bh = ((id & 7) << 2) | (j & 3);
  const int q0 = (j >> 2) << 7;

  const __bf16* Qb = Q + (size_t)bh * (2048 * 64);
  const __bf16* Kb = K + (size_t)bh * (2048 * 64);
  const __bf16* Vb = Vt + (size_t)bh * (64 * 2048);

  __shared__ __attribute__((aligned(16))) __bf16 Kbuf[4][4096];        // 32KB
  __shared__ __attribute__((aligned(16))) __bf16 Vbuf[4][4096];        // 32KB
  __shared__ __attribute__((aligned(16))) __bf16 Plds[4][2][8][16][8];  // 16KB

  bf16x8 qf[2][2];
#pragma unroll
  for (int c = 0; c < 2; c++) {
    const __bf16* qp = Qb + (size_t)(q0 + wave * 32 + c * 16 + l15) * 64 + quad * 8;
    qf[c][0] = *(const bf16x8*)qp;
    qf[c][1] = *(const bf16x8*)(qp + 32);
  }

  const int s0 = (wave * 2 + 0) * 64 + lane;
  const int s1 = (wave * 2 + 1) * 64 + lane;
  const int r0 = s0 >> 3, c0 = (s0 & 7) ^ (r0 & 7);
  const int r1 = s1 >> 3, c1 = (s1 & 7) ^ (r1 & 7);
  const __bf16* kg0 = Kb + r0 * 64 + c0 * 8;
  const __bf16* kg1 = Kb + r1 * 64 + c1 * 8;
  const __bf16* vg0 = Vb + r0 * 2048 + c0 * 8;
  const __bf16* vg1 = Vb + r1 * 2048 + c1 * 8;
  const int kldsA = (wave * 2 + 0) * 512;
  const int kldsB = (wave * 2 + 1) * 512;

  const int offF0 = l15 * 64 + ((quad ^ (l15 & 7)) * 8);
  const int offF1 = l15 * 64 + (((4 + quad) ^ (l15 & 7)) * 8);

  f32x4 rs4[2] = {};
  f32x4 oT[4][2] = {};

  auto stage = [&](int buf, int kt) {
    GLL16(kg0 + kt * 64, &Kbuf[buf][kldsA]);
    GLL16(kg1 + kt * 64, &Kbuf[buf][kldsB]);
    GLL16(vg0 + kt, &Vbuf[buf][kldsA]);
    GLL16(vg1 + kt, &Vbuf[buf][kldsB]);
  };
  auto compute = [&](int buf) {
    f32x4 sT[2][4];
#pragma unroll
    for (int nt = 0; nt < 4; nt++) {
      bf16x8 kf0 = *(const bf16x8*)&Kbuf[buf][nt * 1024 + offF0];
      bf16x8 kf1 = *(const bf16x8*)&Kbuf[buf][nt * 1024 + offF1];
#pragma unroll
      for (int c = 0; c < 2; c++) {
        f32x4 z = {};
        z = MFMA(kf0, qf[c][0], z);
        sT[c][nt] = MFMA(kf1, qf[c][1], z);
      }
    }
#pragma unroll
    for (int c = 0; c < 2; c++) {
#pragma unroll
      for (int nt = 0; nt < 4; nt++) {
        bf16x4 pb;
        f32x4 pe;
#pragma unroll
        for (int r = 0; r < 4; r++) {
          pe[r] = __builtin_amdgcn_exp2f(sT[c][nt][r]);
          pb[r] = (__bf16)pe[r];
        }
        rs4[c] += pe;
        const int chunk = nt * 2 + (quad >> 1);
        *(bf16x4*)&Plds[wave][c][chunk][l15 ^ ((chunk & 3) << 1)][(quad & 1) * 4] = pb;
      }
    }
    bf16x8 pf[2][2];
#pragma unroll
    for (int c = 0; c < 2; c++) {
      pf[c][0] = *(const bf16x8*)&Plds[wave][c][quad][l15 ^ (quad << 1)][0];
      pf[c][1] = *(const bf16x8*)&Plds[wave][c][4 + quad][l15 ^ (quad << 1)][0];
    }
#pragma unroll
    for (int nt = 0; nt < 4; nt++) {
      bf16x8 vf0 = *(const bf16x8*)&Vbuf[buf][nt * 1024 + offF0];
      bf16x8 vf1 = *(const bf16x8*)&Vbuf[buf][nt * 1024 + offF1];
#pragma unroll
      for (int c = 0; c < 2; c++) {
        oT[nt][c] = MFMA(vf0, pf[c][0], oT[nt][c]);
        oT[nt][c] = MFMA(vf1, pf[c][1], oT[nt][c]);
      }
    }
  };

  stage(0, 0);
  stage(1, 64);
  for (int kt = 0; kt < 2048; kt += 128) {
    const int p = (kt >> 7) & 1;
    __syncthreads();
    if (kt + 128 < 2048) {
      stage(2 * (p ^ 1), kt + 128);
      stage(2 * (p ^ 1) + 1, kt + 192);
    }
    compute(2 * p);
    compute(2 * p + 1);
  }

  const int b = bh >> 4, h = bh & 15;
#pragma unroll
  for (int c = 0; c < 2; c++) {
    float l = (rs4[c][0] + rs4[c][1]) + (rs4[c][2] + rs4[c][3]);
    l += __shfl_xor(l, 16, 64);
    l += __shfl_xor(l, 32, 64);
    const float inv = 1.f / l;
    const int q = q0 + wave * 32 + c * 16 + l15;
#pragma unroll
    for (int nt = 0; nt < 4; nt++) {
      bf16x4 o;
#pragma unroll
      for (int r = 0; r < 4; r++) o[r] = (__bf16)(oT[nt][c][r] * inv);
      *(bf16x4*)&Aout[((size_t)(b * 2048 + q)) * 1024 + h * 64 + nt * 16 + quad * 4] = o;
    }
  }
}

extern "C" void kernel_launch(void* const* d_in, const int* in_sizes, int n_in,
                              void* d_out, int out_size, void* d_ws, size_t ws_size,
                              hipStream_t stream) {
  const float* x   = (const float*)d_in[0];
  const float* ctx = (const float*)d_in[1];
  const float* Wq  = (const float*)d_in[2];
  const float* Wv  = (const float*)d_in[3];
  const float* Wo  = (const float*)d_in[4];
  const float* bo  = (const float*)d_in[5];

  char* ws = (char*)d_ws;
  const size_t MB = 1024 * 1024;
  __bf16* xb   = (__bf16*)(ws + 0 * MB);   // [4096,1024]; contiguous with cb
  __bf16* cb   = (__bf16*)(ws + 8 * MB);   // [4096,1024]
  __bf16* Wqb  = (__bf16*)(ws + 16 * MB);  // contiguous with Wvb
  __bf16* Wvb  = (__bf16*)(ws + 18 * MB);
  __bf16* Wob  = (__bf16*)(ws + 20 * MB);
  __bf16* qh   = (__bf16*)(ws + 22 * MB);  // [b,h,s,d], pre-scaled by 0.18034
  __bf16* kh   = (__bf16*)(ws + 30 * MB);  // [b,h,s,d]
  __bf16* vt   = (__bf16*)(ws + 38 * MB);  // [b,h,d,s]
  __bf16* attn = xb;  // xb dead after QK projection

  cvt_all_kernel<<<5632, 256, 0, stream>>>(x, ctx, Wq, Wv, Wo, xb, cb, Wqb, Wvb, Wob);

  gemm_proj<<<768, 256, 0, stream>>>(xb, Wqb, (void*)qh, (void*)kh, (void*)vt);

  attn_kernel<<<512, 256, 0, stream>>>(qh, kh, vt, attn);

  gemm_out<<<1024, 256, 0, stream>>>(attn, Wob, (float*)d_out, bo);
}